// Round 9
// baseline (161.736 us; speedup 1.0000x reference)
//
#include <hip/hip_runtime.h>
#include <hip/hip_bf16.h>

// Problem: B=4, L=2048, D_MODEL=1024, H=16, D_QKV=64.
// Reference einsum 'bhlk,blhd->blhd' contracts k over logits only; softmax sums to 1,
// so attention output == v and the net reduces to:
//   out = x @ Wc + fc_b,  Wc[m][j] = sum_{hd} w_v[h][m][d] * fc_w[j][hd]
// prep (512 blocks x 256 thr): blocks 0-255 fold Wc^T via COALESCED LDS-staged GEMM
//   (r8 profile: old direct-fragment fold was 42us latency-bound — 64 cachelines/wave gather);
//   blocks 256-511 cast x->bf16. Independent, overlapped.
// final_gemm: r7's 151us version verbatim (128x64, BK=64 single-buffer, 1024 blocks, 4/CU).

typedef __attribute__((ext_vector_type(8))) short bf16x8;
typedef __attribute__((ext_vector_type(4))) float f32x4;
typedef __attribute__((ext_vector_type(4))) unsigned short u16x4;

__device__ __forceinline__ f32x4 mfma16(bf16x8 a, bf16x8 b, f32x4 c) {
  return __builtin_amdgcn_mfma_f32_16x16x32_bf16(a, b, c, 0, 0, 0);
}

// fp32 -> bf16 bits, round-to-nearest-even
__device__ __forceinline__ unsigned short f2b(float f) {
  unsigned int u = __builtin_bit_cast(unsigned int, f);
  return (unsigned short)((u + 0x7fffu + ((u >> 16) & 1u)) >> 16);
}

__device__ __forceinline__ bf16x8 cvt8(float4 a, float4 b) {
  bf16x8 r;
  r[0] = (short)f2b(a.x); r[1] = (short)f2b(a.y); r[2] = (short)f2b(a.z); r[3] = (short)f2b(a.w);
  r[4] = (short)f2b(b.x); r[5] = (short)f2b(b.y); r[6] = (short)f2b(b.z); r[7] = (short)f2b(b.w);
  return r;
}

__device__ __forceinline__ u16x4 cvt4(float4 a) {
  u16x4 r;
  r[0] = f2b(a.x); r[1] = f2b(a.y); r[2] = f2b(a.z); r[3] = f2b(a.w);
  return r;
}

// async global->LDS, 16 B per lane (m97 pattern; LDS dest = wave-uniform base + lane*16)
__device__ __forceinline__ void gld_lds16(const void* g, void* l) {
  __builtin_amdgcn_global_load_lds((const __attribute__((address_space(1))) unsigned int*)g,
                                   (__attribute__((address_space(3))) unsigned int*)l, 16, 0, 0);
}

// prep: blocks 0-255 fold Wc^T (coalesced LDS-staged GEMM); blocks 256-511 cast x->bf16.
__global__ __launch_bounds__(256) void prep(const float* __restrict__ x,
                                            const float* __restrict__ wv,
                                            const float* __restrict__ fcw,
                                            unsigned short* __restrict__ xb,
                                            unsigned short* __restrict__ wcT) {
  // fold staging: [k-slab][row][32 bf16] — 64B row stride (m97-proven, conflict-benign)
  __shared__ __align__(16) unsigned short As[2][64 * 32];  // 4 KB each
  __shared__ __align__(16) unsigned short Bs[2][64 * 32];
  int bid = blockIdx.x, t = threadIdx.x;
  int wid = t >> 6, lane = t & 63, l16 = lane & 15, quad = lane >> 4;

  if (bid < 256) {
    // fold: wcT[j][m] = sum_{hd} fcw[j][hd] * wv[hd>>6][m][hd&63]; 64x64 tile,
    // 4 waves 2x2 (32x32 each). BK=64 = one full h-block per stage iteration.
    int j0 = (bid >> 4) * 64, m0 = (bid & 15) * 64;
    int wr = wid >> 1, wc = wid & 1;
    f32x4 acc[2][2];
#pragma unroll
    for (int a = 0; a < 2; a++)
#pragma unroll
      for (int b = 0; b < 2; b++) acc[a][b] = (f32x4){0.f, 0.f, 0.f, 0.f};

    // staging map: thread t loads 4 rows (p*16 + t>>4) x 4 cols ((t&15)*4) as float4.
    // threads 0..15 cover 64 consecutive floats (256B) of one row -> coalesced.
    int lr = t >> 4, lc = (t & 15) * 4;
    int slab = lc >> 5, col = lc & 31;

    for (int h = 0; h < 16; h++) {
      __syncthreads();   // protect previous iteration's LDS reads
#pragma unroll
      for (int p = 0; p < 4; p++) {
        int row = p * 16 + lr;
        float4 a4 = *reinterpret_cast<const float4*>(fcw + (j0 + row) * 1024 + h * 64 + lc);
        float4 b4 = *reinterpret_cast<const float4*>(wv + h * 65536 + (m0 + row) * 64 + lc);
        *reinterpret_cast<u16x4*>(&As[slab][row * 32 + col]) = cvt4(a4);
        *reinterpret_cast<u16x4*>(&Bs[slab][row * 32 + col]) = cvt4(b4);
      }
      __syncthreads();
#pragma unroll
      for (int kh = 0; kh < 2; kh++) {
        bf16x8 af[2], bfr[2];
#pragma unroll
        for (int rt = 0; rt < 2; rt++)
          af[rt] = *reinterpret_cast<const bf16x8*>(&As[kh][(wr * 32 + rt * 16 + l16) * 32 + quad * 8]);
#pragma unroll
        for (int ct = 0; ct < 2; ct++)
          bfr[ct] = *reinterpret_cast<const bf16x8*>(&Bs[kh][(wc * 32 + ct * 16 + l16) * 32 + quad * 8]);
#pragma unroll
        for (int rt = 0; rt < 2; rt++)
#pragma unroll
          for (int ct = 0; ct < 2; ct++) acc[rt][ct] = mfma16(af[rt], bfr[ct], acc[rt][ct]);
      }
    }
#pragma unroll
    for (int rt = 0; rt < 2; rt++)
#pragma unroll
      for (int ct = 0; ct < 2; ct++) {
        int j = j0 + wr * 32 + rt * 16 + quad * 4;
        int m = m0 + wc * 32 + ct * 16 + l16;
#pragma unroll
        for (int r = 0; r < 4; r++) wcT[(j + r) * 1024 + m] = f2b(acc[rt][ct][r]);
      }
  } else {
    // cast: x fp32 -> bf16, 32768 elems per block (contiguous), 16-B ld/st.
    int base0 = (bid - 256) << 15;
#pragma unroll
    for (int i = 0; i < 16; i++) {
      int idx = base0 + i * 2048 + t * 8;
      float4 a = *reinterpret_cast<const float4*>(x + idx);
      float4 b = *reinterpret_cast<const float4*>(x + idx + 4);
      *reinterpret_cast<bf16x8*>(xb + idx) = cvt8(a, b);
    }
  }
}

// out[i][j] = sum_m xb[i][m]*wcT[j][m] + fcb[j].  M=8192,N=1024,K=1024.
// 128x64 tile, BK=64 (two 32-k slabs), 1024 blocks N-fastest (16 blocks share an A M-tile).
// LDS 24KB, 4 blocks/CU for latency hiding. (r7 version verbatim — best known.)
__global__ __launch_bounds__(256, 4) void final_gemm(const unsigned short* __restrict__ xb,
                                                     const unsigned short* __restrict__ wcT,
                                                     const float* __restrict__ fcb,
                                                     float* __restrict__ out) {
  __shared__ __align__(16) unsigned short As[2 * 128 * 32];  // 16 KB  [slab][row][32]
  __shared__ __align__(16) unsigned short Bs[2 * 64 * 32];   //  8 KB
  int t = threadIdx.x, wid = t >> 6, lane = t & 63, l16 = lane & 15, quad = lane >> 4;
  int wr = wid >> 1, wc = wid & 1;
  int row0 = (blockIdx.x >> 4) * 128;   // M tile (64)
  int col0 = (blockIdx.x & 15) * 64;    // N tile (16) — fastest: B stays L2-hot

  int w4 = wid * 4, w2 = wid * 2;
  const unsigned short* Ap[4];
  const unsigned short* Bp[2];
#pragma unroll
  for (int j = 0; j < 4; j++) {
    int blk = w4 + j, s = blk >> 3;
    int row = (blk & 7) * 16 + (lane >> 2), kq = lane & 3;
    Ap[j] = xb + (row0 + row) * 1024 + s * 32 + kq * 8;
  }
#pragma unroll
  for (int j = 0; j < 2; j++) {
    int blk = w2 + j, s = blk >> 2;
    int row = (blk & 3) * 16 + (lane >> 2), kq = lane & 3;
    Bp[j] = wcT + (col0 + row) * 1024 + s * 32 + kq * 8;
  }

  f32x4 acc[4][2];
#pragma unroll
  for (int rt = 0; rt < 4; rt++)
#pragma unroll
    for (int ct = 0; ct < 2; ct++) acc[rt][ct] = (f32x4){0.f, 0.f, 0.f, 0.f};

  for (int k0 = 0; k0 < 1024; k0 += 64) {
    __syncthreads();
#pragma unroll
    for (int j = 0; j < 4; j++) gld_lds16(Ap[j] + k0, &As[(w4 + j) * 512 + lane * 8]);
#pragma unroll
    for (int j = 0; j < 2; j++) gld_lds16(Bp[j] + k0, &Bs[(w2 + j) * 512 + lane * 8]);
    __syncthreads();
#pragma unroll
    for (int s = 0; s < 2; s++) {
      bf16x8 af[4], bfr[2];
#pragma unroll
      for (int rt = 0; rt < 4; rt++)
        af[rt] = *reinterpret_cast<const bf16x8*>(&As[s * 4096 + (wr * 64 + rt * 16 + l16) * 32 + quad * 8]);
#pragma unroll
      for (int ct = 0; ct < 2; ct++)
        bfr[ct] = *reinterpret_cast<const bf16x8*>(&Bs[s * 2048 + (wc * 32 + ct * 16 + l16) * 32 + quad * 8]);
#pragma unroll
      for (int rt = 0; rt < 4; rt++)
#pragma unroll
        for (int ct = 0; ct < 2; ct++)
          acc[rt][ct] = mfma16(af[rt], bfr[ct], acc[rt][ct]);
    }
  }

#pragma unroll
  for (int ct = 0; ct < 2; ct++) {
    int j = col0 + wc * 32 + ct * 16 + l16;
    float bias = fcb[j];
#pragma unroll
    for (int rt = 0; rt < 4; rt++) {
      int i0 = row0 + wr * 64 + rt * 16 + quad * 4;
      f32x4 a = acc[rt][ct];
#pragma unroll
      for (int r = 0; r < 4; r++) out[(i0 + r) * 1024 + j] = a[r] + bias;
    }
  }
}

extern "C" void kernel_launch(void* const* d_in, const int* in_sizes, int n_in,
                              void* d_out, int out_size, void* d_ws, size_t ws_size,
                              hipStream_t stream) {
  const float* x   = (const float*)d_in[0];
  // d_in[1] mask, d_in[2] w_q, d_in[3] w_k: dead per reference semantics
  const float* wv  = (const float*)d_in[4];
  const float* fcw = (const float*)d_in[5];
  const float* fcb = (const float*)d_in[6];
  float* out = (float*)d_out;

  char* ws = (char*)d_ws;
  unsigned short* xb  = (unsigned short*)(ws);              // 16 MB (8192x1024 bf16)
  unsigned short* wcT = (unsigned short*)(ws + 16777216);   // 2 MB  (1024x1024 bf16)

  prep<<<512, 256, 0, stream>>>(x, wv, fcw, xb, wcT);
  final_gemm<<<1024, 256, 0, stream>>>(xb, wcT, fcb, out);
}